// Round 2
// baseline (225.755 us; speedup 1.0000x reference)
//
#include <hip/hip_runtime.h>

// Network_31945966748134: per-row MLP collapse, fully coalesced version.
//   h = relu(x . w_in); 9x relu(w_i*h) == h * prod(max(w_i,0)); softmax(h*w_out).
// Memory-bound: 134 MB read + 101 MB write.
// Block of 256 threads owns 1024 consecutive rows:
//   - loads block-interleaved (lane-contiguous float4) -> perfectly coalesced
//   - results staged in LDS, then written as 3 coalesced float4 stores/thread
//     covering the block's contiguous 12 KB output slice.

#define ROWS_PER_BLOCK 1024

__global__ __launch_bounds__(256) void Network_31945966748134_kernel(
    const float4* __restrict__ xv,
    const float* __restrict__ w_in,
    const float* __restrict__ w_hidden,
    const float* __restrict__ w_out,
    float4* __restrict__ outv,
    int nrows)
{
    __shared__ float lds[ROWS_PER_BLOCK * 3];  // 12 KB

    // Wave-uniform weight loads (scalar path, cached).
    const float wi0 = w_in[0], wi1 = w_in[1], wi2 = w_in[2], wi3 = w_in[3];
    float c = 1.0f;
#pragma unroll
    for (int i = 0; i < 9; ++i) c *= fmaxf(w_hidden[i], 0.0f);
    const float wo0 = w_out[0], wo1 = w_out[1], wo2 = w_out[2];

    const int tid = threadIdx.x;
    const int base = blockIdx.x * ROWS_PER_BLOCK;

#pragma unroll
    for (int k = 0; k < 4; ++k) {
        const int lr = k * 256 + tid;          // local row 0..1023
        const int r = base + lr;
        if (r < nrows) {
            const float4 xs = xv[r];           // coalesced: lane-contiguous float4
            float h = xs.x * wi0 + xs.y * wi1 + xs.z * wi2 + xs.w * wi3;
            h = fmaxf(h, 0.0f) * c;
            const float l0 = h * wo0, l1 = h * wo1, l2 = h * wo2;
            const float m = fmaxf(fmaxf(l0, l1), l2);
            const float e0 = __expf(l0 - m);
            const float e1 = __expf(l1 - m);
            const float e2 = __expf(l2 - m);
            const float inv = 1.0f / (e0 + e1 + e2);
            // stride-3 float writes: banks 3*lane%32 -> 2 lanes/bank (free)
            lds[lr * 3 + 0] = e0 * inv;
            lds[lr * 3 + 1] = e1 * inv;
            lds[lr * 3 + 2] = e2 * inv;
        }
    }
    __syncthreads();

    // Coalesced write-back of the block's contiguous 3072-float output slice.
    const float4* __restrict__ lv = (const float4*)lds;
    const size_t out4base = (size_t)blockIdx.x * (ROWS_PER_BLOCK * 3 / 4);
    const int valid_floats = (min(nrows - base, ROWS_PER_BLOCK)) * 3;
#pragma unroll
    for (int k = 0; k < 3; ++k) {
        const int idx = k * 256 + tid;         // float4 index within block slice
        const int f0 = idx * 4;
        if (f0 + 4 <= valid_floats) {
            outv[out4base + idx] = lv[idx];    // coalesced dwordx4
        } else if (f0 < valid_floats) {
            // ragged tail (only if nrows % 1024 != 0) — scalar fallback
            float* o = (float*)(outv + out4base + idx);
            for (int j = 0; j < valid_floats - f0; ++j) o[j] = lds[f0 + j];
        }
    }
}

extern "C" void kernel_launch(void* const* d_in, const int* in_sizes, int n_in,
                              void* d_out, int out_size, void* d_ws, size_t ws_size,
                              hipStream_t stream) {
    const float* x        = (const float*)d_in[0];
    const float* w_in     = (const float*)d_in[1];
    const float* w_hidden = (const float*)d_in[2];
    const float* w_out    = (const float*)d_in[3];
    float* out = (float*)d_out;

    const int nrows = in_sizes[0] / 4;  // x is [B,4]
    const int grid = (nrows + ROWS_PER_BLOCK - 1) / ROWS_PER_BLOCK;
    Network_31945966748134_kernel<<<grid, 256, 0, stream>>>(
        (const float4*)x, w_in, w_hidden, w_out, (float4*)out, nrows);
}

// Round 6
// 216.130 us; speedup vs baseline: 1.0445x; 1.0445x over previous
//
#include <hip/hip_runtime.h>

// Network_31945966748134: per-row MLP collapse, coalesced + non-temporal.
//   h = relu(x . w_in); 9x relu(w_i*h) == h * prod(max(w_i,0)); softmax(h*w_out).
// Memory-bound: 134 MB read (mostly L3-resident after harness restore) +
// 101 MB write. Block of 256 threads owns 1024 consecutive rows:
//   - loads lane-contiguous float4 (perfectly coalesced), nt hint (read-once)
//   - results staged in 12 KB LDS, written back as 3 lane-contiguous
//     non-temporal float4 stores per thread (write-once stream).
// NOTE: __builtin_nontemporal_* requires a clang-native vector type, not
// HIP_vector_type — use ext_vector_type(4) float.

typedef float f32x4 __attribute__((ext_vector_type(4)));

#define ROWS_PER_BLOCK 1024

__global__ __launch_bounds__(256) void Network_31945966748134_kernel(
    const f32x4* __restrict__ xv,
    const float* __restrict__ w_in,
    const float* __restrict__ w_hidden,
    const float* __restrict__ w_out,
    f32x4* __restrict__ outv,
    int nrows)
{
    __shared__ float lds[ROWS_PER_BLOCK * 3];  // 12 KB

    // Wave-uniform weight loads (scalar path, cached).
    const float wi0 = w_in[0], wi1 = w_in[1], wi2 = w_in[2], wi3 = w_in[3];
    float c = 1.0f;
#pragma unroll
    for (int i = 0; i < 9; ++i) c *= fmaxf(w_hidden[i], 0.0f);
    const float wo0 = w_out[0], wo1 = w_out[1], wo2 = w_out[2];

    const int tid = threadIdx.x;
    const int base = blockIdx.x * ROWS_PER_BLOCK;

#pragma unroll
    for (int k = 0; k < 4; ++k) {
        const int lr = k * 256 + tid;          // local row 0..1023
        const int r = base + lr;
        if (r < nrows) {
            const f32x4 xs = __builtin_nontemporal_load(&xv[r]);  // coalesced
            float h = xs.x * wi0 + xs.y * wi1 + xs.z * wi2 + xs.w * wi3;
            h = fmaxf(h, 0.0f) * c;
            const float l0 = h * wo0, l1 = h * wo1, l2 = h * wo2;
            const float m = fmaxf(fmaxf(l0, l1), l2);
            const float e0 = __expf(l0 - m);
            const float e1 = __expf(l1 - m);
            const float e2 = __expf(l2 - m);
            const float inv = 1.0f / (e0 + e1 + e2);
            // stride-3 float writes: 2 lanes/bank max (free per m136)
            lds[lr * 3 + 0] = e0 * inv;
            lds[lr * 3 + 1] = e1 * inv;
            lds[lr * 3 + 2] = e2 * inv;
        }
    }
    __syncthreads();

    // Coalesced non-temporal write-back of the block's contiguous slice.
    const f32x4* __restrict__ lv = (const f32x4*)lds;
    const size_t out4base = (size_t)blockIdx.x * (ROWS_PER_BLOCK * 3 / 4);
    const int valid_floats = (min(nrows - base, ROWS_PER_BLOCK)) * 3;
#pragma unroll
    for (int k = 0; k < 3; ++k) {
        const int idx = k * 256 + tid;         // float4 index within block slice
        const int f0 = idx * 4;
        if (f0 + 4 <= valid_floats) {
            __builtin_nontemporal_store(lv[idx], &outv[out4base + idx]);
        } else if (f0 < valid_floats) {
            float* o = (float*)(outv + out4base + idx);
            for (int j = 0; j < valid_floats - f0; ++j) o[j] = lds[f0 + j];
        }
    }
}

extern "C" void kernel_launch(void* const* d_in, const int* in_sizes, int n_in,
                              void* d_out, int out_size, void* d_ws, size_t ws_size,
                              hipStream_t stream) {
    const float* x        = (const float*)d_in[0];
    const float* w_in     = (const float*)d_in[1];
    const float* w_hidden = (const float*)d_in[2];
    const float* w_out    = (const float*)d_in[3];
    float* out = (float*)d_out;

    const int nrows = in_sizes[0] / 4;  // x is [B,4]
    const int grid = (nrows + ROWS_PER_BLOCK - 1) / ROWS_PER_BLOCK;
    Network_31945966748134_kernel<<<grid, 256, 0, stream>>>(
        (const f32x4*)x, w_in, w_hidden, w_out, (f32x4*)out, nrows);
}